// Round 3
// 1853.343 us; speedup vs baseline: 1.0643x; 1.0643x over previous
//
#include <hip/hip_runtime.h>
#include <hip/hip_bf16.h>

// Fused Llama layer: B=2 S=2048 H=2048 NH=16 HD=128 INTER=5504 R=16
#define B_ 2
#define S_ 2048
#define H_ 2048
#define NH_ 16
#define HD_ 128
#define INTER_ 5504
#define M_ (B_*S_)

using bf16x8 = __attribute__((ext_vector_type(8))) short;
using f32x4  = __attribute__((ext_vector_type(4))) float;

__device__ __forceinline__ float b2f(unsigned short u) {
  union { unsigned u; float f; } c; c.u = ((unsigned)u) << 16; return c.f;
}
__device__ __forceinline__ short f2b(float f) {
  union { float f; unsigned u; } c; c.f = f;
  unsigned r = (c.u + 0x7fffu + ((c.u >> 16) & 1u)) >> 16;
  return (short)r;
}

typedef const __attribute__((address_space(1))) void* gvp;
typedef __attribute__((address_space(3))) void* lvp;
__device__ __forceinline__ void gl2lds16(const short* g, short* l) {
  __builtin_amdgcn_global_load_lds((gvp)g, (lvp)l, 16, 0, 0);
}

// ---------------- fp32 -> bf16 weight convert (vectorized) ----------------
__global__ void k_f2b(const float* __restrict__ in, short* __restrict__ out, int n) {
  int i = (blockIdx.x * 256 + threadIdx.x) * 4;
  if (i < n) {
    float4 f = *(const float4*)(in + i);
    short4 o4; o4.x = f2b(f.x); o4.y = f2b(f.y); o4.z = f2b(f.z); o4.w = f2b(f.w);
    *(short4*)(out + i) = o4;
  }
}

// ---------------- RMSNorm (fp32 in, bf16 out) ----------------
__global__ __launch_bounds__(256) void k_rmsnorm(const float* __restrict__ x,
                                                 const float* __restrict__ w,
                                                 short* __restrict__ out) {
  int row = blockIdx.x;
  const float4* xr = (const float4*)(x + (long)row * H_);
  float ss = 0.f;
  float4 v[2];
#pragma unroll
  for (int it = 0; it < 2; ++it) {
    float4 t = xr[threadIdx.x + it * 256];
    v[it] = t;
    ss += t.x*t.x + t.y*t.y + t.z*t.z + t.w*t.w;
  }
#pragma unroll
  for (int o = 32; o; o >>= 1) ss += __shfl_xor(ss, o);
  __shared__ float s4[4];
  if ((threadIdx.x & 63) == 0) s4[threadIdx.x >> 6] = ss;
  __syncthreads();
  float r = rsqrtf((s4[0] + s4[1] + s4[2] + s4[3]) * (1.f / H_) + 1e-5f);
  const float4* wr = (const float4*)w;
  short4* orow = (short4*)(out + (long)row * H_);
#pragma unroll
  for (int it = 0; it < 2; ++it) {
    float4 t = v[it];
    float4 ww = wr[threadIdx.x + it * 256];
    short4 o4;
    o4.x = f2b(t.x * r * ww.x); o4.y = f2b(t.y * r * ww.y);
    o4.z = f2b(t.z * r * ww.z); o4.w = f2b(t.w * r * ww.w);
    orow[threadIdx.x + it * 256] = o4;
  }
}

// ---------------- LoRA T = Xn @ A^T ----------------
__global__ __launch_bounds__(256) void k_lora_t(const short* __restrict__ Xn,
                                                const float* __restrict__ A,
                                                short* __restrict__ T2, int K) {
  int m = blockIdx.x;
  int g = threadIdx.x & 15;
  int r = threadIdx.x >> 4;
  const short* xr = Xn + (long)m * K;
  const float* ar = A + (long)r * K;
  float p = 0.f;
  for (int k = g; k < K; k += 16) p += b2f((unsigned short)xr[k]) * ar[k];
  __shared__ float red[256];
  red[threadIdx.x] = p;
  __syncthreads();
  if (threadIdx.x < 32) {
    float s = 0.f;
    if (threadIdx.x < 16) {
      int rr = threadIdx.x;
#pragma unroll
      for (int gg = 0; gg < 16; ++gg) s += red[rr * 16 + gg];
    }
    T2[(long)m * 32 + threadIdx.x] = (threadIdx.x < 16) ? f2b(s) : (short)0;
  }
}

// ---------------- Bm [N,16] fp32 -> Bm2 [N,32] bf16 zero-padded ----------------
__global__ void k_prep_bm2(const float* __restrict__ Bm, short* __restrict__ Bm2, int N) {
  int i = blockIdx.x * 256 + threadIdx.x;
  if (i >= N * 32) return;
  int c = i & 31, n = i >> 5;
  Bm2[i] = (c < 16) ? f2b(Bm[(long)n * 16 + c]) : (short)0;
}

// ---------------- QKV GEMM (LDS-staged) + RoPE + transpose ----------------
__global__ __launch_bounds__(256) void k_gemm_qkv(
    const short* __restrict__ A, const short* __restrict__ W,
    const float* __restrict__ bias,
    const short* __restrict__ T2, const short* __restrict__ Bm2,
    const float* __restrict__ cs, const float* __restrict__ sn,
    short* __restrict__ out, int do_rope) {
  const int K = H_;
  __shared__ short As[128 * 32];
  __shared__ short Bs[128 * 32];
  int t = threadIdx.x;
  int lane = t & 63, wave = t >> 6;
  int row0 = blockIdx.y * 128;
  int col0 = blockIdx.x * 128;
  int lr = lane & 15, lk = (lane >> 4) << 3;
  int srow = t >> 2, skc = t & 3;
  const short* Ag0 = A + (long)(row0 + srow) * K + skc * 8;
  const short* Ag1 = A + (long)(row0 + 64 + srow) * K + skc * 8;
  const short* Wg0 = W + (long)(col0 + srow) * K + skc * 8;
  const short* Wg1 = W + (long)(col0 + 64 + srow) * K + skc * 8;
  short* Al0 = As + wave * 512;
  short* Al1 = As + 2048 + wave * 512;
  short* Bl0 = Bs + wave * 512;
  short* Bl1 = Bs + 2048 + wave * 512;
  f32x4 acc[2][8] = {};
  for (int k0 = 0; k0 < K; k0 += 32) {
    gl2lds16(Ag0 + k0, Al0);
    gl2lds16(Ag1 + k0, Al1);
    gl2lds16(Wg0 + k0, Bl0);
    gl2lds16(Wg1 + k0, Bl1);
    __syncthreads();
    bf16x8 a[2], b[8];
#pragma unroll
    for (int i = 0; i < 2; ++i) a[i] = *(const bf16x8*)(As + (wave * 32 + i * 16 + lr) * 32 + lk);
#pragma unroll
    for (int j = 0; j < 8; ++j) b[j] = *(const bf16x8*)(Bs + (j * 16 + lr) * 32 + lk);
#pragma unroll
    for (int i = 0; i < 2; ++i)
#pragma unroll
      for (int j = 0; j < 8; ++j)
        acc[i][j] = __builtin_amdgcn_mfma_f32_16x16x32_bf16(a[i], b[j], acc[i][j], 0, 0, 0);
    __syncthreads();
  }
  { // LoRA K-extension
    bf16x8 a[2], b[8];
#pragma unroll
    for (int i = 0; i < 2; ++i) a[i] = *(const bf16x8*)(T2 + (long)(row0 + wave * 32 + i * 16 + lr) * 32 + lk);
#pragma unroll
    for (int j = 0; j < 8; ++j) b[j] = *(const bf16x8*)(Bm2 + (long)(col0 + j * 16 + lr) * 32 + lk);
#pragma unroll
    for (int i = 0; i < 2; ++i)
#pragma unroll
      for (int j = 0; j < 8; ++j)
        acc[i][j] = __builtin_amdgcn_mfma_f32_16x16x32_bf16(a[i], b[j], acc[i][j], 0, 0, 0);
  }
  int rquad = (lane >> 4) * 4;
  int head = blockIdx.x;
#pragma unroll
  for (int i = 0; i < 2; ++i) {
#pragma unroll
    for (int tt = 0; tt < 4; ++tt) {
      int row = row0 + wave * 32 + i * 16 + rquad + tt;
      int bb = row >> 11, sr = row & (S_ - 1);
      float vals[8];
#pragma unroll
      for (int j = 0; j < 8; ++j) vals[j] = acc[i][j][tt] + bias[col0 + j * 16 + lr];
      long obase = ((long)(bb * NH_ + head) * S_ + sr) * HD_;
      if (do_rope) {
#pragma unroll
        for (int j = 0; j < 8; ++j) {
          int d = j * 16 + lr;
          float rot = (j < 4) ? -vals[j + 4] : vals[j - 4];
          out[obase + d] = f2b(vals[j] * cs[sr * HD_ + d] + rot * sn[sr * HD_ + d]);
        }
      } else {
#pragma unroll
        for (int j = 0; j < 8; ++j) out[obase + j * 16 + lr] = f2b(vals[j]);
      }
    }
  }
}

// ---------------- General GEMM (LDS-staged) ----------------
__global__ __launch_bounds__(256) void k_gemm(
    const short* __restrict__ A, const short* __restrict__ W,
    const float* __restrict__ bias,
    const short* __restrict__ T2, const short* __restrict__ Bm2,
    const float* __restrict__ resid, const short* gatebf, int do_silu,
    float* __restrict__ outf, short* outb,
    int N, int K) {
  __shared__ short As[128 * 32];
  __shared__ short Bs[128 * 32];
  int t = threadIdx.x;
  int lane = t & 63, wave = t >> 6;
  int wm = wave >> 1, wn = wave & 1;
  int row0 = blockIdx.y * 128;
  int col0 = blockIdx.x * 128;
  int lr = lane & 15, lk = (lane >> 4) << 3;
  int srow = t >> 2, skc = t & 3;
  const short* Ag0 = A + (long)(row0 + srow) * K + skc * 8;
  const short* Ag1 = A + (long)(row0 + 64 + srow) * K + skc * 8;
  const short* Wg0 = W + (long)(col0 + srow) * K + skc * 8;
  const short* Wg1 = W + (long)(col0 + 64 + srow) * K + skc * 8;
  short* Al0 = As + wave * 512;
  short* Al1 = As + 2048 + wave * 512;
  short* Bl0 = Bs + wave * 512;
  short* Bl1 = Bs + 2048 + wave * 512;
  f32x4 acc[4][4] = {};
  for (int k0 = 0; k0 < K; k0 += 32) {
    gl2lds16(Ag0 + k0, Al0);
    gl2lds16(Ag1 + k0, Al1);
    gl2lds16(Wg0 + k0, Bl0);
    gl2lds16(Wg1 + k0, Bl1);
    __syncthreads();
    bf16x8 a[4], b[4];
#pragma unroll
    for (int i = 0; i < 4; ++i) a[i] = *(const bf16x8*)(As + (wm * 64 + i * 16 + lr) * 32 + lk);
#pragma unroll
    for (int j = 0; j < 4; ++j) b[j] = *(const bf16x8*)(Bs + (wn * 64 + j * 16 + lr) * 32 + lk);
#pragma unroll
    for (int i = 0; i < 4; ++i)
#pragma unroll
      for (int j = 0; j < 4; ++j)
        acc[i][j] = __builtin_amdgcn_mfma_f32_16x16x32_bf16(a[i], b[j], acc[i][j], 0, 0, 0);
    __syncthreads();
  }
  { // LoRA K-extension
    bf16x8 a[4], b[4];
#pragma unroll
    for (int i = 0; i < 4; ++i) a[i] = *(const bf16x8*)(T2 + (long)(row0 + wm * 64 + i * 16 + lr) * 32 + lk);
#pragma unroll
    for (int j = 0; j < 4; ++j) b[j] = *(const bf16x8*)(Bm2 + (long)(col0 + wn * 64 + j * 16 + lr) * 32 + lk);
#pragma unroll
    for (int i = 0; i < 4; ++i)
#pragma unroll
      for (int j = 0; j < 4; ++j)
        acc[i][j] = __builtin_amdgcn_mfma_f32_16x16x32_bf16(a[i], b[j], acc[i][j], 0, 0, 0);
  }
  int rquad = (lane >> 4) * 4;
#pragma unroll
  for (int i = 0; i < 4; ++i) {
#pragma unroll
    for (int j = 0; j < 4; ++j) {
      int col = col0 + wn * 64 + j * 16 + lr;
      float bc = bias[col];
#pragma unroll
      for (int tt = 0; tt < 4; ++tt) {
        int row = row0 + wm * 64 + i * 16 + rquad + tt;
        long idx = (long)row * N + col;
        float v2 = acc[i][j][tt] + bc;
        if (do_silu) v2 = v2 / (1.f + __expf(-v2));
        if (gatebf) v2 *= b2f((unsigned short)gatebf[idx]);
        if (resid) v2 += resid[idx];
        if (outf) outf[idx] = v2;
        else outb[idx] = f2b(v2);
      }
    }
  }
}

// ---------------- V transpose: [bh][s][d] -> [bh][d][s] (bf16) ----------------
__global__ __launch_bounds__(256) void k_vtrans(const short* __restrict__ in,
                                                short* __restrict__ out) {
  __shared__ short tb[64][72];
  int t = threadIdx.x;
  int s0 = blockIdx.x * 64, d0 = blockIdx.y * 64, bh = blockIdx.z;
  long ibase = (long)bh * S_ * HD_;
  long obase = (long)bh * HD_ * S_;
  int r = t >> 2, c = t & 3;
#pragma unroll
  for (int cc = 0; cc < 2; ++cc) {
    int ch = c + cc * 4;
    *(uint4*)&tb[r][ch * 8] = *(const uint4*)(in + ibase + (long)(s0 + r) * HD_ + d0 + ch * 8);
  }
  __syncthreads();
  int d = t >> 2;
#pragma unroll
  for (int cc = 0; cc < 2; ++cc) {
    int ch = c + cc * 4;
    short v[8];
#pragma unroll
    for (int ii = 0; ii < 8; ++ii) v[ii] = tb[ch * 8 + ii][d];
    *(uint4*)(out + obase + (long)(d0 + d) * S_ + s0 + ch * 8) = *(uint4*)v;
  }
}

// ---------------- MFMA flash attention (causal) + K/V double-buffer --------
// IDENTICAL compute/softmax/epilogue to the proven kernel; only changes:
// (1) K/V tiles double-buffered, ONE barrier per k-iter, stage(kb+1) issued
//     right after the barrier so its HBM latency hides under this iter's
//     64 MFMAs + softmax (drains at the NEXT barrier's vmcnt(0)).
// (2) defensive explicit s_waitcnt before the barrier (insurance that all
//     in-flight global_load_lds have landed even if the compiler's implicit
//     barrier-drain were dependency-gated).
// (3) block order heavy-tiles-first (qb = 15 - blk>>5) for LPT backfill
//     balance at 1 block/CU (LDS 83 KB); bh = blk&31 groups a head's blocks
//     on one XCD for K/V L2 locality.
__global__ __launch_bounds__(256) void k_attn(const short* __restrict__ Q,
                                              const short* __restrict__ Kg,
                                              const short* __restrict__ Vt,
                                              short* __restrict__ att) {
  __shared__ __align__(16) short Kls[2][4][64 * 32];   // [buf][ks][key*32]
  __shared__ __align__(16) short Vls[2][2][128 * 32];  // [buf][kv][d*32]
  __shared__ __align__(16) short Pl[4][32 * 72];       // per-wave [q][72]
  __shared__ float al[4][32];
  __shared__ float ll[4][32];
  int t = threadIdx.x, lane = t & 63, wave = t >> 6;
  int lr = lane & 15, quad = lane >> 4;
  int bh = blockIdx.x & 31;
  int qb = 15 - (blockIdx.x >> 5);     // heavy tiles dispatched first
  int q0 = qb * 128;
  int qlo = q0 + wave * 32;
  long base = (long)bh * S_ * HD_;
  long vbase = (long)bh * HD_ * S_;
  const float c1 = 0.08838834764831845f * 1.44269504089f;  // scale*log2e
  // Q fragments (registers, once per block)
  bf16x8 qf[2][4];
#pragma unroll
  for (int i = 0; i < 2; ++i)
#pragma unroll
    for (int ks = 0; ks < 4; ++ks)
      qf[i][ks] = *(const bf16x8*)(Q + base + (long)(qlo + i * 16 + lr) * HD_ + ks * 32 + quad * 8);
  f32x4 oacc[8][2] = {};
  float m_i[2][4], l_i[2][4];
#pragma unroll
  for (int i = 0; i < 2; ++i)
#pragma unroll
    for (int tt = 0; tt < 4; ++tt) { m_i[i][tt] = -3.0e38f; l_i[i][tt] = 0.f; }
  int sk_row = lane >> 2, sk_c = lane & 3;
  auto stage = [&](int buf, int kb) {
    int kk0 = kb << 6;
    // K tile k-major: wave handles k-slice ks=wave
#pragma unroll
    for (int i = 0; i < 4; ++i)
      gl2lds16(Kg + base + (long)(kk0 + i * 16 + sk_row) * HD_ + wave * 32 + sk_c * 8,
               &Kls[buf][wave][i * 512]);
    // V^T tile k-major: wave handles d-range wave*32..+31
#pragma unroll
    for (int kv = 0; kv < 2; ++kv)
#pragma unroll
      for (int db = 0; db < 2; ++db)
        gl2lds16(Vt + vbase + (long)(wave * 32 + db * 16 + sk_row) * S_ + kk0 + kv * 32 + sk_c * 8,
                 &Vls[buf][kv][(wave * 32 + db * 16) * 32]);
  };
  int kbmax = (q0 + 127) >> 6;
  stage(0, 0);
  int cur = 0;
  for (int kb = 0; kb <= kbmax; ++kb) {
    int kk0 = kb << 6;
    asm volatile("s_waitcnt vmcnt(0) lgkmcnt(0)" ::: "memory");
    __syncthreads();                       // buf[cur] staged; prev-iter reads done
    if (kb < kbmax) stage(cur ^ 1, kb + 1);
    if (kk0 <= qlo + 31) {
      // S = Q K^T
      f32x4 s[2][4] = {};
#pragma unroll
      for (int ks = 0; ks < 4; ++ks) {
        bf16x8 kf[4];
#pragma unroll
        for (int j = 0; j < 4; ++j) kf[j] = *(const bf16x8*)&Kls[cur][ks][(j * 16 + lr) * 32 + quad * 8];
#pragma unroll
        for (int i = 0; i < 2; ++i)
#pragma unroll
          for (int j = 0; j < 4; ++j)
            s[i][j] = __builtin_amdgcn_mfma_f32_16x16x32_bf16(qf[i][ks], kf[j], s[i][j], 0, 0, 0);
      }
      // causal mask (only diagonal-region tiles)
      if (kk0 + 63 > qlo) {
#pragma unroll
        for (int i = 0; i < 2; ++i)
#pragma unroll
          for (int j = 0; j < 4; ++j) {
            int key = kk0 + j * 16 + lr;
#pragma unroll
            for (int tt = 0; tt < 4; ++tt) {
              int qrow = qlo + i * 16 + quad * 4 + tt;
              if (key > qrow) s[i][j][tt] = -1.0e30f;
            }
          }
      }
      // online softmax per row (raw domain, scale in exp2 args)
#pragma unroll
      for (int i = 0; i < 2; ++i) {
#pragma unroll
        for (int tt = 0; tt < 4; ++tt) {
          float mx = fmaxf(fmaxf(s[i][0][tt], s[i][1][tt]), fmaxf(s[i][2][tt], s[i][3][tt]));
#pragma unroll
          for (int o = 1; o < 16; o <<= 1) mx = fmaxf(mx, __shfl_xor(mx, o));
          float mold = m_i[i][tt];
          float mnew = fmaxf(mold, mx);
          float alpha = exp2f((mold - mnew) * c1);
          float mc = mnew * c1;
          float rs = 0.f;
#pragma unroll
          for (int j = 0; j < 4; ++j) {
            float p = exp2f(s[i][j][tt] * c1 - mc);
            s[i][j][tt] = p;
            rs += p;
          }
#pragma unroll
          for (int o = 1; o < 16; o <<= 1) rs += __shfl_xor(rs, o);
          l_i[i][tt] = l_i[i][tt] * alpha + rs;
          m_i[i][tt] = mnew;
          if (lr == 0) al[wave][i * 16 + quad * 4 + tt] = alpha;
        }
      }
      // P -> LDS (bf16, padded rows)
#pragma unroll
      for (int i = 0; i < 2; ++i)
#pragma unroll
        for (int j = 0; j < 4; ++j)
#pragma unroll
          for (int tt = 0; tt < 4; ++tt)
            Pl[wave][(i * 16 + quad * 4 + tt) * 72 + j * 16 + lr] = f2b(s[i][j][tt]);
      // rescale O accumulator by alpha[q]
#pragma unroll
      for (int i2 = 0; i2 < 2; ++i2) {
        float aq = al[wave][i2 * 16 + lr];
#pragma unroll
        for (int mi = 0; mi < 8; ++mi) {
          oacc[mi][i2][0] *= aq; oacc[mi][i2][1] *= aq;
          oacc[mi][i2][2] *= aq; oacc[mi][i2][3] *= aq;
        }
      }
      // O^T += V^T * P   (A = V^T tile, B = P)
#pragma unroll
      for (int kv = 0; kv < 2; ++kv) {
        bf16x8 pf[2];
#pragma unroll
        for (int i2 = 0; i2 < 2; ++i2)
          pf[i2] = *(const bf16x8*)&Pl[wave][(i2 * 16 + lr) * 72 + kv * 32 + quad * 8];
#pragma unroll
        for (int mi = 0; mi < 8; ++mi) {
          bf16x8 vfr = *(const bf16x8*)&Vls[cur][kv][(mi * 16 + lr) * 32 + quad * 8];
#pragma unroll
          for (int i2 = 0; i2 < 2; ++i2)
            oacc[mi][i2] = __builtin_amdgcn_mfma_f32_16x16x32_bf16(vfr, pf[i2], oacc[mi][i2], 0, 0, 0);
        }
      }
    }
    cur ^= 1;
  }
  // epilogue: divide by l, store O[q][d] as short4 along d
#pragma unroll
  for (int i = 0; i < 2; ++i)
#pragma unroll
    for (int tt = 0; tt < 4; ++tt)
      if (lr == 0) ll[wave][i * 16 + quad * 4 + tt] = l_i[i][tt];
  int b = bh >> 4, h = bh & (NH_ - 1);
#pragma unroll
  for (int i2 = 0; i2 < 2; ++i2) {
    float inv = 1.f / ll[wave][i2 * 16 + lr];
    int q_abs = qlo + i2 * 16 + lr;
    long ob = ((long)(b * S_ + q_abs)) * H_ + h * HD_;
#pragma unroll
    for (int mi = 0; mi < 8; ++mi) {
      short4 o4;
      o4.x = f2b(oacc[mi][i2][0] * inv);
      o4.y = f2b(oacc[mi][i2][1] * inv);
      o4.z = f2b(oacc[mi][i2][2] * inv);
      o4.w = f2b(oacc[mi][i2][3] * inv);
      *(short4*)(att + ob + mi * 16 + quad * 4) = o4;
    }
  }
}

// ---------------- host ----------------
extern "C" void kernel_launch(void* const* d_in, const int* in_sizes, int n_in,
                              void* d_out, int out_size, void* d_ws, size_t ws_size,
                              hipStream_t stream) {
  const float* x    = (const float*)d_in[0];
  const float* nw1  = (const float*)d_in[1];
  const float* nw2  = (const float*)d_in[2];
  const float* cosb = (const float*)d_in[3];
  const float* sinb = (const float*)d_in[4];
  const float *W[7], *Bias[7], *La[7], *Lb[7];
  for (int p = 0; p < 7; ++p) {
    W[p]    = (const float*)d_in[5 + p * 4];
    Bias[p] = (const float*)d_in[6 + p * 4];
    La[p]   = (const float*)d_in[7 + p * 4];
    Lb[p]   = (const float*)d_in[8 + p * 4];
  }
  const int wsz[7] = {H_*H_, H_*H_, H_*H_, H_*H_, INTER_*H_, INTER_*H_, INTER_*H_};

  char* ws = (char*)d_ws;
  size_t off = 0;
  short* wbuf = (short*)(ws + off); off += (size_t)INTER_ * H_ * 2;
  short* T2   = (short*)(ws + off); off += (size_t)M_ * 32 * 2;
  short* Bm2  = (short*)(ws + off); off += (size_t)INTER_ * 32 * 2;
  short* xn   = (short*)(ws + off); off += (size_t)M_ * H_ * 2;
  char*  regC = ws + off;           off += (size_t)M_ * H_ * 2 * 3;
  short* gact = (short*)(ws + off); off += (size_t)M_ * INTER_ * 2;
  short* qr = (short*)regC;
  short* kr = (short*)(regC + (size_t)M_ * H_ * 2);
  short* vr = (short*)(regC + (size_t)M_ * H_ * 2 * 2);
  float* xmed = (float*)regC;
  short* vt   = gact;               // vt lifetime ends before gact starts
  short* attb = xn;
  float* outp = (float*)d_out;

  auto conv = [&](int p) {
    k_f2b<<<dim3((wsz[p] / 4 + 255) / 256), dim3(256), 0, stream>>>(W[p], wbuf, wsz[p]);
  };
  auto lora = [&](int p, const short* Ain, int K, int N) {
    k_lora_t<<<dim3(M_), dim3(256), 0, stream>>>(Ain, La[p], T2, K);
    k_prep_bm2<<<dim3((N * 32 + 255) / 256), dim3(256), 0, stream>>>(Lb[p], Bm2, N);
  };

  // 1. RMSNorm 1
  k_rmsnorm<<<dim3(M_), dim3(256), 0, stream>>>(x, nw1, xn);
  // 2. Q,K,V projections fused with RoPE + transpose -> [B,NH,S,HD]
  conv(0); lora(0, xn, H_, H_);
  k_gemm_qkv<<<dim3(NH_, M_ / 128), dim3(256), 0, stream>>>(xn, wbuf, Bias[0], T2, Bm2, cosb, sinb, qr, 1);
  conv(1); lora(1, xn, H_, H_);
  k_gemm_qkv<<<dim3(NH_, M_ / 128), dim3(256), 0, stream>>>(xn, wbuf, Bias[1], T2, Bm2, cosb, sinb, kr, 1);
  conv(2); lora(2, xn, H_, H_);
  k_gemm_qkv<<<dim3(NH_, M_ / 128), dim3(256), 0, stream>>>(xn, wbuf, Bias[2], T2, Bm2, cosb, sinb, vr, 0);
  // 3. V transpose -> vt [bh][d][s]
  k_vtrans<<<dim3(S_ / 64, HD_ / 64, B_ * NH_), dim3(256), 0, stream>>>(vr, vt);
  // 4. MFMA flash attention (K/V dbuf, heavy-first order) -> attb [B,S,H] bf16
  k_attn<<<dim3(B_ * NH_ * (S_ / 128)), dim3(256), 0, stream>>>(qr, kr, vt, attb);
  // 5. O projection + residual(x) -> xmed fp32
  conv(3); lora(3, attb, H_, H_);
  k_gemm<<<dim3(H_ / 128, M_ / 128), dim3(256), 0, stream>>>(
      attb, wbuf, Bias[3], T2, Bm2, x, nullptr, 0, xmed, nullptr, H_, H_);
  // 6. RMSNorm 2 -> xn
  k_rmsnorm<<<dim3(M_), dim3(256), 0, stream>>>(xmed, nw2, xn);
  // 7. gate -> silu(gate) bf16
  conv(4); lora(4, xn, H_, INTER_);
  k_gemm<<<dim3(INTER_ / 128, M_ / 128), dim3(256), 0, stream>>>(
      xn, wbuf, Bias[4], T2, Bm2, nullptr, nullptr, 1, nullptr, gact, INTER_, H_);
  // 8. up * silu(gate) -> gact in place
  conv(5); lora(5, xn, H_, INTER_);
  k_gemm<<<dim3(INTER_ / 128, M_ / 128), dim3(256), 0, stream>>>(
      xn, wbuf, Bias[5], T2, Bm2, nullptr, gact, 0, nullptr, gact, INTER_, H_);
  // 9. down + residual(xmed) -> d_out fp32
  conv(6); lora(6, gact, INTER_, H_);
  k_gemm<<<dim3(H_ / 128, M_ / 128), dim3(256), 0, stream>>>(
      gact, wbuf, Bias[6], T2, Bm2, xmed, nullptr, 0, outp, nullptr, H_, INTER_);
}

// Round 4
// 1374.484 us; speedup vs baseline: 1.4351x; 1.3484x over previous
//
#include <hip/hip_runtime.h>
#include <hip/hip_bf16.h>

// Fused Llama layer: B=2 S=2048 H=2048 NH=16 HD=128 INTER=5504 R=16
#define B_ 2
#define S_ 2048
#define H_ 2048
#define NH_ 16
#define HD_ 128
#define INTER_ 5504
#define M_ (B_*S_)

using bf16x8 = __attribute__((ext_vector_type(8))) short;
using f32x4  = __attribute__((ext_vector_type(4))) float;

__device__ __forceinline__ float b2f(unsigned short u) {
  union { unsigned u; float f; } c; c.u = ((unsigned)u) << 16; return c.f;
}
__device__ __forceinline__ short f2b(float f) {
  union { float f; unsigned u; } c; c.f = f;
  unsigned r = (c.u + 0x7fffu + ((c.u >> 16) & 1u)) >> 16;
  return (short)r;
}

typedef const __attribute__((address_space(1))) void* gvp;
typedef __attribute__((address_space(3))) void* lvp;
__device__ __forceinline__ void gl2lds16(const short* g, short* l) {
  __builtin_amdgcn_global_load_lds((gvp)g, (lvp)l, 16, 0, 0);
}

// ---------------- fp32 -> bf16 weight convert (vectorized) ----------------
__global__ void k_f2b(const float* __restrict__ in, short* __restrict__ out, int n) {
  int i = (blockIdx.x * 256 + threadIdx.x) * 4;
  if (i < n) {
    float4 f = *(const float4*)(in + i);
    short4 o4; o4.x = f2b(f.x); o4.y = f2b(f.y); o4.z = f2b(f.z); o4.w = f2b(f.w);
    *(short4*)(out + i) = o4;
  }
}

// ---------------- RMSNorm (fp32 in, bf16 out) ----------------
__global__ __launch_bounds__(256) void k_rmsnorm(const float* __restrict__ x,
                                                 const float* __restrict__ w,
                                                 short* __restrict__ out) {
  int row = blockIdx.x;
  const float4* xr = (const float4*)(x + (long)row * H_);
  float ss = 0.f;
  float4 v[2];
#pragma unroll
  for (int it = 0; it < 2; ++it) {
    float4 t = xr[threadIdx.x + it * 256];
    v[it] = t;
    ss += t.x*t.x + t.y*t.y + t.z*t.z + t.w*t.w;
  }
#pragma unroll
  for (int o = 32; o; o >>= 1) ss += __shfl_xor(ss, o);
  __shared__ float s4[4];
  if ((threadIdx.x & 63) == 0) s4[threadIdx.x >> 6] = ss;
  __syncthreads();
  float r = rsqrtf((s4[0] + s4[1] + s4[2] + s4[3]) * (1.f / H_) + 1e-5f);
  const float4* wr = (const float4*)w;
  short4* orow = (short4*)(out + (long)row * H_);
#pragma unroll
  for (int it = 0; it < 2; ++it) {
    float4 t = v[it];
    float4 ww = wr[threadIdx.x + it * 256];
    short4 o4;
    o4.x = f2b(t.x * r * ww.x); o4.y = f2b(t.y * r * ww.y);
    o4.z = f2b(t.z * r * ww.z); o4.w = f2b(t.w * r * ww.w);
    orow[threadIdx.x + it * 256] = o4;
  }
}

// ---------------- LoRA T = Xn @ A^T (vectorized) ----------------
// One block per row m. Phase 1: stage row into LDS (coalesced bf16x8).
// Phase 2: quarter-wave (16 lanes, same rank r=t>>4) scans A row r
// cooperatively: lane g reads float4 at k = it*64 + g*4 -> 256B coalesced
// per quarter-wave per iter; x from LDS short4. K % 64 == 0 (2048, 5504).
// Phase 3: same 256->16 reduction + zero-padded T2 write as before.
__global__ __launch_bounds__(256) void k_lora_t(const short* __restrict__ Xn,
                                                const float* __restrict__ A,
                                                short* __restrict__ T2, int K) {
  int m = blockIdx.x;
  __shared__ short xrow[INTER_];   // max K = 5504 bf16 = 10.75 KB
  const short* xr = Xn + (long)m * K;
  for (int i = threadIdx.x * 8; i < K; i += 256 * 8)
    *(bf16x8*)(xrow + i) = *(const bf16x8*)(xr + i);
  __syncthreads();
  int g = threadIdx.x & 15;
  int r = threadIdx.x >> 4;
  const float* ar = A + (long)r * K;
  float p = 0.f;
  int nit = K >> 6;                // K/64
  for (int it = 0; it < nit; ++it) {
    int k = it * 64 + g * 4;
    float4 a = *(const float4*)(ar + k);
    short4 xv = *(const short4*)(xrow + k);
    p += b2f((unsigned short)xv.x) * a.x + b2f((unsigned short)xv.y) * a.y
       + b2f((unsigned short)xv.z) * a.z + b2f((unsigned short)xv.w) * a.w;
  }
  __shared__ float red[256];
  red[threadIdx.x] = p;
  __syncthreads();
  if (threadIdx.x < 32) {
    float s = 0.f;
    if (threadIdx.x < 16) {
      int rr = threadIdx.x;
#pragma unroll
      for (int gg = 0; gg < 16; ++gg) s += red[rr * 16 + gg];
    }
    T2[(long)m * 32 + threadIdx.x] = (threadIdx.x < 16) ? f2b(s) : (short)0;
  }
}

// ---------------- Bm [N,16] fp32 -> Bm2 [N,32] bf16 zero-padded ----------------
__global__ void k_prep_bm2(const float* __restrict__ Bm, short* __restrict__ Bm2, int N) {
  int i = blockIdx.x * 256 + threadIdx.x;
  if (i >= N * 32) return;
  int c = i & 31, n = i >> 5;
  Bm2[i] = (c < 16) ? f2b(Bm[(long)n * 16 + c]) : (short)0;
}

// ---------------- QKV GEMM (LDS-staged) + RoPE + transpose ----------------
__global__ __launch_bounds__(256) void k_gemm_qkv(
    const short* __restrict__ A, const short* __restrict__ W,
    const float* __restrict__ bias,
    const short* __restrict__ T2, const short* __restrict__ Bm2,
    const float* __restrict__ cs, const float* __restrict__ sn,
    short* __restrict__ out, int do_rope) {
  const int K = H_;
  __shared__ short As[128 * 32];
  __shared__ short Bs[128 * 32];
  int t = threadIdx.x;
  int lane = t & 63, wave = t >> 6;
  int row0 = blockIdx.y * 128;
  int col0 = blockIdx.x * 128;
  int lr = lane & 15, lk = (lane >> 4) << 3;
  int srow = t >> 2, skc = t & 3;
  const short* Ag0 = A + (long)(row0 + srow) * K + skc * 8;
  const short* Ag1 = A + (long)(row0 + 64 + srow) * K + skc * 8;
  const short* Wg0 = W + (long)(col0 + srow) * K + skc * 8;
  const short* Wg1 = W + (long)(col0 + 64 + srow) * K + skc * 8;
  short* Al0 = As + wave * 512;
  short* Al1 = As + 2048 + wave * 512;
  short* Bl0 = Bs + wave * 512;
  short* Bl1 = Bs + 2048 + wave * 512;
  f32x4 acc[2][8] = {};
  for (int k0 = 0; k0 < K; k0 += 32) {
    gl2lds16(Ag0 + k0, Al0);
    gl2lds16(Ag1 + k0, Al1);
    gl2lds16(Wg0 + k0, Bl0);
    gl2lds16(Wg1 + k0, Bl1);
    __syncthreads();
    bf16x8 a[2], b[8];
#pragma unroll
    for (int i = 0; i < 2; ++i) a[i] = *(const bf16x8*)(As + (wave * 32 + i * 16 + lr) * 32 + lk);
#pragma unroll
    for (int j = 0; j < 8; ++j) b[j] = *(const bf16x8*)(Bs + (j * 16 + lr) * 32 + lk);
#pragma unroll
    for (int i = 0; i < 2; ++i)
#pragma unroll
      for (int j = 0; j < 8; ++j)
        acc[i][j] = __builtin_amdgcn_mfma_f32_16x16x32_bf16(a[i], b[j], acc[i][j], 0, 0, 0);
    __syncthreads();
  }
  { // LoRA K-extension
    bf16x8 a[2], b[8];
#pragma unroll
    for (int i = 0; i < 2; ++i) a[i] = *(const bf16x8*)(T2 + (long)(row0 + wave * 32 + i * 16 + lr) * 32 + lk);
#pragma unroll
    for (int j = 0; j < 8; ++j) b[j] = *(const bf16x8*)(Bm2 + (long)(col0 + j * 16 + lr) * 32 + lk);
#pragma unroll
    for (int i = 0; i < 2; ++i)
#pragma unroll
      for (int j = 0; j < 8; ++j)
        acc[i][j] = __builtin_amdgcn_mfma_f32_16x16x32_bf16(a[i], b[j], acc[i][j], 0, 0, 0);
  }
  int rquad = (lane >> 4) * 4;
  int head = blockIdx.x;
#pragma unroll
  for (int i = 0; i < 2; ++i) {
#pragma unroll
    for (int tt = 0; tt < 4; ++tt) {
      int row = row0 + wave * 32 + i * 16 + rquad + tt;
      int bb = row >> 11, sr = row & (S_ - 1);
      float vals[8];
#pragma unroll
      for (int j = 0; j < 8; ++j) vals[j] = acc[i][j][tt] + bias[col0 + j * 16 + lr];
      long obase = ((long)(bb * NH_ + head) * S_ + sr) * HD_;
      if (do_rope) {
#pragma unroll
        for (int j = 0; j < 8; ++j) {
          int d = j * 16 + lr;
          float rot = (j < 4) ? -vals[j + 4] : vals[j - 4];
          out[obase + d] = f2b(vals[j] * cs[sr * HD_ + d] + rot * sn[sr * HD_ + d]);
        }
      } else {
#pragma unroll
        for (int j = 0; j < 8; ++j) out[obase + j * 16 + lr] = f2b(vals[j]);
      }
    }
  }
}

// ---------------- General GEMM (LDS-staged) ----------------
__global__ __launch_bounds__(256) void k_gemm(
    const short* __restrict__ A, const short* __restrict__ W,
    const float* __restrict__ bias,
    const short* __restrict__ T2, const short* __restrict__ Bm2,
    const float* __restrict__ resid, const short* gatebf, int do_silu,
    float* __restrict__ outf, short* outb,
    int N, int K) {
  __shared__ short As[128 * 32];
  __shared__ short Bs[128 * 32];
  int t = threadIdx.x;
  int lane = t & 63, wave = t >> 6;
  int wm = wave >> 1, wn = wave & 1;
  int row0 = blockIdx.y * 128;
  int col0 = blockIdx.x * 128;
  int lr = lane & 15, lk = (lane >> 4) << 3;
  int srow = t >> 2, skc = t & 3;
  const short* Ag0 = A + (long)(row0 + srow) * K + skc * 8;
  const short* Ag1 = A + (long)(row0 + 64 + srow) * K + skc * 8;
  const short* Wg0 = W + (long)(col0 + srow) * K + skc * 8;
  const short* Wg1 = W + (long)(col0 + 64 + srow) * K + skc * 8;
  short* Al0 = As + wave * 512;
  short* Al1 = As + 2048 + wave * 512;
  short* Bl0 = Bs + wave * 512;
  short* Bl1 = Bs + 2048 + wave * 512;
  f32x4 acc[4][4] = {};
  for (int k0 = 0; k0 < K; k0 += 32) {
    gl2lds16(Ag0 + k0, Al0);
    gl2lds16(Ag1 + k0, Al1);
    gl2lds16(Wg0 + k0, Bl0);
    gl2lds16(Wg1 + k0, Bl1);
    __syncthreads();
    bf16x8 a[4], b[4];
#pragma unroll
    for (int i = 0; i < 4; ++i) a[i] = *(const bf16x8*)(As + (wm * 64 + i * 16 + lr) * 32 + lk);
#pragma unroll
    for (int j = 0; j < 4; ++j) b[j] = *(const bf16x8*)(Bs + (wn * 64 + j * 16 + lr) * 32 + lk);
#pragma unroll
    for (int i = 0; i < 4; ++i)
#pragma unroll
      for (int j = 0; j < 4; ++j)
        acc[i][j] = __builtin_amdgcn_mfma_f32_16x16x32_bf16(a[i], b[j], acc[i][j], 0, 0, 0);
    __syncthreads();
  }
  { // LoRA K-extension
    bf16x8 a[4], b[4];
#pragma unroll
    for (int i = 0; i < 4; ++i) a[i] = *(const bf16x8*)(T2 + (long)(row0 + wm * 64 + i * 16 + lr) * 32 + lk);
#pragma unroll
    for (int j = 0; j < 4; ++j) b[j] = *(const bf16x8*)(Bm2 + (long)(col0 + wn * 64 + j * 16 + lr) * 32 + lk);
#pragma unroll
    for (int i = 0; i < 4; ++i)
#pragma unroll
      for (int j = 0; j < 4; ++j)
        acc[i][j] = __builtin_amdgcn_mfma_f32_16x16x32_bf16(a[i], b[j], acc[i][j], 0, 0, 0);
  }
  int rquad = (lane >> 4) * 4;
#pragma unroll
  for (int i = 0; i < 4; ++i) {
#pragma unroll
    for (int j = 0; j < 4; ++j) {
      int col = col0 + wn * 64 + j * 16 + lr;
      float bc = bias[col];
#pragma unroll
      for (int tt = 0; tt < 4; ++tt) {
        int row = row0 + wm * 64 + i * 16 + rquad + tt;
        long idx = (long)row * N + col;
        float v2 = acc[i][j][tt] + bc;
        if (do_silu) v2 = v2 / (1.f + __expf(-v2));
        if (gatebf) v2 *= b2f((unsigned short)gatebf[idx]);
        if (resid) v2 += resid[idx];
        if (outf) outf[idx] = v2;
        else outb[idx] = f2b(v2);
      }
    }
  }
}

// ---------------- V transpose: [bh][s][d] -> [bh][d][s] (bf16) ----------------
__global__ __launch_bounds__(256) void k_vtrans(const short* __restrict__ in,
                                                short* __restrict__ out) {
  __shared__ short tb[64][72];
  int t = threadIdx.x;
  int s0 = blockIdx.x * 64, d0 = blockIdx.y * 64, bh = blockIdx.z;
  long ibase = (long)bh * S_ * HD_;
  long obase = (long)bh * HD_ * S_;
  int r = t >> 2, c = t & 3;
#pragma unroll
  for (int cc = 0; cc < 2; ++cc) {
    int ch = c + cc * 4;
    *(uint4*)&tb[r][ch * 8] = *(const uint4*)(in + ibase + (long)(s0 + r) * HD_ + d0 + ch * 8);
  }
  __syncthreads();
  int d = t >> 2;
#pragma unroll
  for (int cc = 0; cc < 2; ++cc) {
    int ch = c + cc * 4;
    short v[8];
#pragma unroll
    for (int ii = 0; ii < 8; ++ii) v[ii] = tb[ch * 8 + ii][d];
    *(uint4*)(out + obase + (long)(d0 + d) * S_ + s0 + ch * 8) = *(uint4*)v;
  }
}

// ---------------- MFMA flash attention (causal) + K/V double-buffer --------
__global__ __launch_bounds__(256) void k_attn(const short* __restrict__ Q,
                                              const short* __restrict__ Kg,
                                              const short* __restrict__ Vt,
                                              short* __restrict__ att) {
  __shared__ __align__(16) short Kls[2][4][64 * 32];   // [buf][ks][key*32]
  __shared__ __align__(16) short Vls[2][2][128 * 32];  // [buf][kv][d*32]
  __shared__ __align__(16) short Pl[4][32 * 72];       // per-wave [q][72]
  __shared__ float al[4][32];
  __shared__ float ll[4][32];
  int t = threadIdx.x, lane = t & 63, wave = t >> 6;
  int lr = lane & 15, quad = lane >> 4;
  int bh = blockIdx.x & 31;
  int qb = 15 - (blockIdx.x >> 5);     // heavy tiles dispatched first
  int q0 = qb * 128;
  int qlo = q0 + wave * 32;
  long base = (long)bh * S_ * HD_;
  long vbase = (long)bh * HD_ * S_;
  const float c1 = 0.08838834764831845f * 1.44269504089f;  // scale*log2e
  // Q fragments (registers, once per block)
  bf16x8 qf[2][4];
#pragma unroll
  for (int i = 0; i < 2; ++i)
#pragma unroll
    for (int ks = 0; ks < 4; ++ks)
      qf[i][ks] = *(const bf16x8*)(Q + base + (long)(qlo + i * 16 + lr) * HD_ + ks * 32 + quad * 8);
  f32x4 oacc[8][2] = {};
  float m_i[2][4], l_i[2][4];
#pragma unroll
  for (int i = 0; i < 2; ++i)
#pragma unroll
    for (int tt = 0; tt < 4; ++tt) { m_i[i][tt] = -3.0e38f; l_i[i][tt] = 0.f; }
  int sk_row = lane >> 2, sk_c = lane & 3;
  auto stage = [&](int buf, int kb) {
    int kk0 = kb << 6;
#pragma unroll
    for (int i = 0; i < 4; ++i)
      gl2lds16(Kg + base + (long)(kk0 + i * 16 + sk_row) * HD_ + wave * 32 + sk_c * 8,
               &Kls[buf][wave][i * 512]);
#pragma unroll
    for (int kv = 0; kv < 2; ++kv)
#pragma unroll
      for (int db = 0; db < 2; ++db)
        gl2lds16(Vt + vbase + (long)(wave * 32 + db * 16 + sk_row) * S_ + kk0 + kv * 32 + sk_c * 8,
                 &Vls[buf][kv][(wave * 32 + db * 16) * 32]);
  };
  int kbmax = (q0 + 127) >> 6;
  stage(0, 0);
  int cur = 0;
  for (int kb = 0; kb <= kbmax; ++kb) {
    int kk0 = kb << 6;
    asm volatile("s_waitcnt vmcnt(0) lgkmcnt(0)" ::: "memory");
    __syncthreads();                       // buf[cur] staged; prev-iter reads done
    if (kb < kbmax) stage(cur ^ 1, kb + 1);
    if (kk0 <= qlo + 31) {
      // S = Q K^T
      f32x4 s[2][4] = {};
#pragma unroll
      for (int ks = 0; ks < 4; ++ks) {
        bf16x8 kf[4];
#pragma unroll
        for (int j = 0; j < 4; ++j) kf[j] = *(const bf16x8*)&Kls[cur][ks][(j * 16 + lr) * 32 + quad * 8];
#pragma unroll
        for (int i = 0; i < 2; ++i)
#pragma unroll
          for (int j = 0; j < 4; ++j)
            s[i][j] = __builtin_amdgcn_mfma_f32_16x16x32_bf16(qf[i][ks], kf[j], s[i][j], 0, 0, 0);
      }
      // causal mask (only diagonal-region tiles)
      if (kk0 + 63 > qlo) {
#pragma unroll
        for (int i = 0; i < 2; ++i)
#pragma unroll
          for (int j = 0; j < 4; ++j) {
            int key = kk0 + j * 16 + lr;
#pragma unroll
            for (int tt = 0; tt < 4; ++tt) {
              int qrow = qlo + i * 16 + quad * 4 + tt;
              if (key > qrow) s[i][j][tt] = -1.0e30f;
            }
          }
      }
      // online softmax per row (raw domain, scale in exp2 args)
#pragma unroll
      for (int i = 0; i < 2; ++i) {
#pragma unroll
        for (int tt = 0; tt < 4; ++tt) {
          float mx = fmaxf(fmaxf(s[i][0][tt], s[i][1][tt]), fmaxf(s[i][2][tt], s[i][3][tt]));
#pragma unroll
          for (int o = 1; o < 16; o <<= 1) mx = fmaxf(mx, __shfl_xor(mx, o));
          float mold = m_i[i][tt];
          float mnew = fmaxf(mold, mx);
          float alpha = exp2f((mold - mnew) * c1);
          float mc = mnew * c1;
          float rs = 0.f;
#pragma unroll
          for (int j = 0; j < 4; ++j) {
            float p = exp2f(s[i][j][tt] * c1 - mc);
            s[i][j][tt] = p;
            rs += p;
          }
#pragma unroll
          for (int o = 1; o < 16; o <<= 1) rs += __shfl_xor(rs, o);
          l_i[i][tt] = l_i[i][tt] * alpha + rs;
          m_i[i][tt] = mnew;
          if (lr == 0) al[wave][i * 16 + quad * 4 + tt] = alpha;
        }
      }
      // P -> LDS (bf16, padded rows)
#pragma unroll
      for (int i = 0; i < 2; ++i)
#pragma unroll
        for (int j = 0; j < 4; ++j)
#pragma unroll
          for (int tt = 0; tt < 4; ++tt)
            Pl[wave][(i * 16 + quad * 4 + tt) * 72 + j * 16 + lr] = f2b(s[i][j][tt]);
      // rescale O accumulator by alpha[q]
#pragma unroll
      for (int i2 = 0; i2 < 2; ++i2) {
        float aq = al[wave][i2 * 16 + lr];
#pragma unroll
        for (int mi = 0; mi < 8; ++mi) {
          oacc[mi][i2][0] *= aq; oacc[mi][i2][1] *= aq;
          oacc[mi][i2][2] *= aq; oacc[mi][i2][3] *= aq;
        }
      }
      // O^T += V^T * P   (A = V^T tile, B = P)
#pragma unroll
      for (int kv = 0; kv < 2; ++kv) {
        bf16x8 pf[2];
#pragma unroll
        for (int i2 = 0; i2 < 2; ++i2)
          pf[i2] = *(const bf16x8*)&Pl[wave][(i2 * 16 + lr) * 72 + kv * 32 + quad * 8];
#pragma unroll
        for (int mi = 0; mi < 8; ++mi) {
          bf16x8 vfr = *(const bf16x8*)&Vls[cur][kv][(mi * 16 + lr) * 32 + quad * 8];
#pragma unroll
          for (int i2 = 0; i2 < 2; ++i2)
            oacc[mi][i2] = __builtin_amdgcn_mfma_f32_16x16x32_bf16(vfr, pf[i2], oacc[mi][i2], 0, 0, 0);
        }
      }
    }
    cur ^= 1;
  }
  // epilogue: divide by l, store O[q][d] as short4 along d
#pragma unroll
  for (int i = 0; i < 2; ++i)
#pragma unroll
    for (int tt = 0; tt < 4; ++tt)
      if (lr == 0) ll[wave][i * 16 + quad * 4 + tt] = l_i[i][tt];
  int b = bh >> 4, h = bh & (NH_ - 1);
#pragma unroll
  for (int i2 = 0; i2 < 2; ++i2) {
    float inv = 1.f / ll[wave][i2 * 16 + lr];
    int q_abs = qlo + i2 * 16 + lr;
    long ob = ((long)(b * S_ + q_abs)) * H_ + h * HD_;
#pragma unroll
    for (int mi = 0; mi < 8; ++mi) {
      short4 o4;
      o4.x = f2b(oacc[mi][i2][0] * inv);
      o4.y = f2b(oacc[mi][i2][1] * inv);
      o4.z = f2b(oacc[mi][i2][2] * inv);
      o4.w = f2b(oacc[mi][i2][3] * inv);
      *(short4*)(att + ob + mi * 16 + quad * 4) = o4;
    }
  }
}

// ---------------- host ----------------
extern "C" void kernel_launch(void* const* d_in, const int* in_sizes, int n_in,
                              void* d_out, int out_size, void* d_ws, size_t ws_size,
                              hipStream_t stream) {
  const float* x    = (const float*)d_in[0];
  const float* nw1  = (const float*)d_in[1];
  const float* nw2  = (const float*)d_in[2];
  const float* cosb = (const float*)d_in[3];
  const float* sinb = (const float*)d_in[4];
  const float *W[7], *Bias[7], *La[7], *Lb[7];
  for (int p = 0; p < 7; ++p) {
    W[p]    = (const float*)d_in[5 + p * 4];
    Bias[p] = (const float*)d_in[6 + p * 4];
    La[p]   = (const float*)d_in[7 + p * 4];
    Lb[p]   = (const float*)d_in[8 + p * 4];
  }
  const int wsz[7] = {H_*H_, H_*H_, H_*H_, H_*H_, INTER_*H_, INTER_*H_, INTER_*H_};

  char* ws = (char*)d_ws;
  size_t off = 0;
  short* wbuf = (short*)(ws + off); off += (size_t)INTER_ * H_ * 2;
  short* T2   = (short*)(ws + off); off += (size_t)M_ * 32 * 2;
  short* Bm2  = (short*)(ws + off); off += (size_t)INTER_ * 32 * 2;
  short* xn   = (short*)(ws + off); off += (size_t)M_ * H_ * 2;
  char*  regC = ws + off;           off += (size_t)M_ * H_ * 2 * 3;
  short* gact = (short*)(ws + off); off += (size_t)M_ * INTER_ * 2;
  short* qr = (short*)regC;
  short* kr = (short*)(regC + (size_t)M_ * H_ * 2);
  short* vr = (short*)(regC + (size_t)M_ * H_ * 2 * 2);
  float* xmed = (float*)regC;
  short* vt   = gact;               // vt lifetime ends before gact starts
  short* attb = xn;
  float* outp = (float*)d_out;

  auto conv = [&](int p) {
    k_f2b<<<dim3((wsz[p] / 4 + 255) / 256), dim3(256), 0, stream>>>(W[p], wbuf, wsz[p]);
  };
  auto lora = [&](int p, const short* Ain, int K, int N) {
    k_lora_t<<<dim3(M_), dim3(256), 0, stream>>>(Ain, La[p], T2, K);
    k_prep_bm2<<<dim3((N * 32 + 255) / 256), dim3(256), 0, stream>>>(Lb[p], Bm2, N);
  };

  // 1. RMSNorm 1
  k_rmsnorm<<<dim3(M_), dim3(256), 0, stream>>>(x, nw1, xn);
  // 2. Q,K,V projections fused with RoPE + transpose -> [B,NH,S,HD]
  conv(0); lora(0, xn, H_, H_);
  k_gemm_qkv<<<dim3(NH_, M_ / 128), dim3(256), 0, stream>>>(xn, wbuf, Bias[0], T2, Bm2, cosb, sinb, qr, 1);
  conv(1); lora(1, xn, H_, H_);
  k_gemm_qkv<<<dim3(NH_, M_ / 128), dim3(256), 0, stream>>>(xn, wbuf, Bias[1], T2, Bm2, cosb, sinb, kr, 1);
  conv(2); lora(2, xn, H_, H_);
  k_gemm_qkv<<<dim3(NH_, M_ / 128), dim3(256), 0, stream>>>(xn, wbuf, Bias[2], T2, Bm2, cosb, sinb, vr, 0);
  // 3. V transpose -> vt [bh][d][s]
  k_vtrans<<<dim3(S_ / 64, HD_ / 64, B_ * NH_), dim3(256), 0, stream>>>(vr, vt);
  // 4. MFMA flash attention (K/V dbuf, heavy-first order) -> attb [B,S,H] bf16
  k_attn<<<dim3(B_ * NH_ * (S_ / 128)), dim3(256), 0, stream>>>(qr, kr, vt, attb);
  // 5. O projection + residual(x) -> xmed fp32
  conv(3); lora(3, attb, H_, H_);
  k_gemm<<<dim3(H_ / 128, M_ / 128), dim3(256), 0, stream>>>(
      attb, wbuf, Bias[3], T2, Bm2, x, nullptr, 0, xmed, nullptr, H_, H_);
  // 6. RMSNorm 2 -> xn
  k_rmsnorm<<<dim3(M_), dim3(256), 0, stream>>>(xmed, nw2, xn);
  // 7. gate -> silu(gate) bf16
  conv(4); lora(4, xn, H_, INTER_);
  k_gemm<<<dim3(INTER_ / 128, M_ / 128), dim3(256), 0, stream>>>(
      xn, wbuf, Bias[4], T2, Bm2, nullptr, nullptr, 1, nullptr, gact, INTER_, H_);
  // 8. up * silu(gate) -> gact in place
  conv(5); lora(5, xn, H_, INTER_);
  k_gemm<<<dim3(INTER_ / 128, M_ / 128), dim3(256), 0, stream>>>(
      xn, wbuf, Bias[5], T2, Bm2, nullptr, gact, 0, nullptr, gact, INTER_, H_);
  // 9. down + residual(xmed) -> d_out fp32
  conv(6); lora(6, gact, INTER_, H_);
  k_gemm<<<dim3(H_ / 128, M_ / 128), dim3(256), 0, stream>>>(
      gact, wbuf, Bias[6], T2, Bm2, xmed, nullptr, 0, outp, nullptr, H_, INTER_);
}

// Round 6
// 1350.737 us; speedup vs baseline: 1.4603x; 1.0176x over previous
//
#include <hip/hip_runtime.h>
#include <hip/hip_bf16.h>

// Fused Llama layer: B=2 S=2048 H=2048 NH=16 HD=128 INTER=5504 R=16
#define B_ 2
#define S_ 2048
#define H_ 2048
#define NH_ 16
#define HD_ 128
#define INTER_ 5504
#define M_ (B_*S_)

using bf16x8 = __attribute__((ext_vector_type(8))) short;
using f32x4  = __attribute__((ext_vector_type(4))) float;

__device__ __forceinline__ float b2f(unsigned short u) {
  union { unsigned u; float f; } c; c.u = ((unsigned)u) << 16; return c.f;
}
__device__ __forceinline__ short f2b(float f) {
  union { float f; unsigned u; } c; c.f = f;
  unsigned r = (c.u + 0x7fffu + ((c.u >> 16) & 1u)) >> 16;
  return (short)r;
}

typedef const __attribute__((address_space(1))) void* gvp;
typedef __attribute__((address_space(3))) void* lvp;
__device__ __forceinline__ void gl2lds16(const short* g, short* l) {
  __builtin_amdgcn_global_load_lds((gvp)g, (lvp)l, 16, 0, 0);
}

// ---------------- fp32 -> bf16 weight convert (vectorized) ----------------
__global__ void k_f2b(const float* __restrict__ in, short* __restrict__ out, int n) {
  int i = (blockIdx.x * 256 + threadIdx.x) * 4;
  if (i < n) {
    float4 f = *(const float4*)(in + i);
    short4 o4; o4.x = f2b(f.x); o4.y = f2b(f.y); o4.z = f2b(f.z); o4.w = f2b(f.w);
    *(short4*)(out + i) = o4;
  }
}

// ---------------- RMSNorm (fp32 in, bf16 out) ----------------
__global__ __launch_bounds__(256) void k_rmsnorm(const float* __restrict__ x,
                                                 const float* __restrict__ w,
                                                 short* __restrict__ out) {
  int row = blockIdx.x;
  const float4* xr = (const float4*)(x + (long)row * H_);
  float ss = 0.f;
  float4 v[2];
#pragma unroll
  for (int it = 0; it < 2; ++it) {
    float4 t = xr[threadIdx.x + it * 256];
    v[it] = t;
    ss += t.x*t.x + t.y*t.y + t.z*t.z + t.w*t.w;
  }
#pragma unroll
  for (int o = 32; o; o >>= 1) ss += __shfl_xor(ss, o);
  __shared__ float s4[4];
  if ((threadIdx.x & 63) == 0) s4[threadIdx.x >> 6] = ss;
  __syncthreads();
  float r = rsqrtf((s4[0] + s4[1] + s4[2] + s4[3]) * (1.f / H_) + 1e-5f);
  const float4* wr = (const float4*)w;
  short4* orow = (short4*)(out + (long)row * H_);
#pragma unroll
  for (int it = 0; it < 2; ++it) {
    float4 t = v[it];
    float4 ww = wr[threadIdx.x + it * 256];
    short4 o4;
    o4.x = f2b(t.x * r * ww.x); o4.y = f2b(t.y * r * ww.y);
    o4.z = f2b(t.z * r * ww.z); o4.w = f2b(t.w * r * ww.w);
    orow[threadIdx.x + it * 256] = o4;
  }
}

// ---------------- LoRA T = Xn @ A^T (vectorized) ----------------
__global__ __launch_bounds__(256) void k_lora_t(const short* __restrict__ Xn,
                                                const float* __restrict__ A,
                                                short* __restrict__ T2, int K) {
  int m = blockIdx.x;
  __shared__ short xrow[INTER_];   // max K = 5504 bf16 = 10.75 KB
  const short* xr = Xn + (long)m * K;
  for (int i = threadIdx.x * 8; i < K; i += 256 * 8)
    *(bf16x8*)(xrow + i) = *(const bf16x8*)(xr + i);
  __syncthreads();
  int g = threadIdx.x & 15;
  int r = threadIdx.x >> 4;
  const float* ar = A + (long)r * K;
  float p = 0.f;
  int nit = K >> 6;                // K/64
  for (int it = 0; it < nit; ++it) {
    int k = it * 64 + g * 4;
    float4 a = *(const float4*)(ar + k);
    short4 xv = *(const short4*)(xrow + k);
    p += b2f((unsigned short)xv.x) * a.x + b2f((unsigned short)xv.y) * a.y
       + b2f((unsigned short)xv.z) * a.z + b2f((unsigned short)xv.w) * a.w;
  }
  __shared__ float red[256];
  red[threadIdx.x] = p;
  __syncthreads();
  if (threadIdx.x < 32) {
    float s = 0.f;
    if (threadIdx.x < 16) {
      int rr = threadIdx.x;
#pragma unroll
      for (int gg = 0; gg < 16; ++gg) s += red[rr * 16 + gg];
    }
    T2[(long)m * 32 + threadIdx.x] = (threadIdx.x < 16) ? f2b(s) : (short)0;
  }
}

// ---------------- Bm [N,16] fp32 -> Bm2 [N,32] bf16 zero-padded ----------------
__global__ void k_prep_bm2(const float* __restrict__ Bm, short* __restrict__ Bm2, int N) {
  int i = blockIdx.x * 256 + threadIdx.x;
  if (i >= N * 32) return;
  int c = i & 31, n = i >> 5;
  Bm2[i] = (c < 16) ? f2b(Bm[(long)n * 16 + c]) : (short)0;
}

// ---------------- QKV GEMM (LDS dbuf staged) + RoPE + transpose ----------------
// 2-phase pipeline: stage(k0+32) issued right after the single per-iter
// barrier; its HBM latency hides under this iter's 16 MFMAs + LDS reads.
__global__ __launch_bounds__(256) void k_gemm_qkv(
    const short* __restrict__ A, const short* __restrict__ W,
    const float* __restrict__ bias,
    const short* __restrict__ T2, const short* __restrict__ Bm2,
    const float* __restrict__ cs, const float* __restrict__ sn,
    short* __restrict__ out, int do_rope) {
  const int K = H_;
  __shared__ short As[2][128 * 32];
  __shared__ short Bs[2][128 * 32];
  int t = threadIdx.x;
  int lane = t & 63, wave = t >> 6;
  int row0 = blockIdx.y * 128;
  int col0 = blockIdx.x * 128;
  int lr = lane & 15, lk = (lane >> 4) << 3;
  int srow = t >> 2, skc = t & 3;
  const short* Ag0 = A + (long)(row0 + srow) * K + skc * 8;
  const short* Ag1 = A + (long)(row0 + 64 + srow) * K + skc * 8;
  const short* Wg0 = W + (long)(col0 + srow) * K + skc * 8;
  const short* Wg1 = W + (long)(col0 + 64 + srow) * K + skc * 8;
  auto stage = [&](int buf, int k0) {
    gl2lds16(Ag0 + k0, &As[buf][wave * 512]);
    gl2lds16(Ag1 + k0, &As[buf][2048 + wave * 512]);
    gl2lds16(Wg0 + k0, &Bs[buf][wave * 512]);
    gl2lds16(Wg1 + k0, &Bs[buf][2048 + wave * 512]);
  };
  f32x4 acc[2][8] = {};
  stage(0, 0);
  int cur = 0;
  for (int k0 = 0; k0 < K; k0 += 32) {
    asm volatile("s_waitcnt vmcnt(0) lgkmcnt(0)" ::: "memory");
    __syncthreads();                     // buf[cur] staged; prev-iter reads done
    if (k0 + 32 < K) stage(cur ^ 1, k0 + 32);
    bf16x8 a[2], b[8];
#pragma unroll
    for (int i = 0; i < 2; ++i) a[i] = *(const bf16x8*)(&As[cur][(wave * 32 + i * 16 + lr) * 32 + lk]);
#pragma unroll
    for (int j = 0; j < 8; ++j) b[j] = *(const bf16x8*)(&Bs[cur][(j * 16 + lr) * 32 + lk]);
#pragma unroll
    for (int i = 0; i < 2; ++i)
#pragma unroll
      for (int j = 0; j < 8; ++j)
        acc[i][j] = __builtin_amdgcn_mfma_f32_16x16x32_bf16(a[i], b[j], acc[i][j], 0, 0, 0);
    cur ^= 1;
  }
  { // LoRA K-extension
    bf16x8 a[2], b[8];
#pragma unroll
    for (int i = 0; i < 2; ++i) a[i] = *(const bf16x8*)(T2 + (long)(row0 + wave * 32 + i * 16 + lr) * 32 + lk);
#pragma unroll
    for (int j = 0; j < 8; ++j) b[j] = *(const bf16x8*)(Bm2 + (long)(col0 + j * 16 + lr) * 32 + lk);
#pragma unroll
    for (int i = 0; i < 2; ++i)
#pragma unroll
      for (int j = 0; j < 8; ++j)
        acc[i][j] = __builtin_amdgcn_mfma_f32_16x16x32_bf16(a[i], b[j], acc[i][j], 0, 0, 0);
  }
  int rquad = (lane >> 4) * 4;
  int head = blockIdx.x;
#pragma unroll
  for (int i = 0; i < 2; ++i) {
#pragma unroll
    for (int tt = 0; tt < 4; ++tt) {
      int row = row0 + wave * 32 + i * 16 + rquad + tt;
      int bb = row >> 11, sr = row & (S_ - 1);
      float vals[8];
#pragma unroll
      for (int j = 0; j < 8; ++j) vals[j] = acc[i][j][tt] + bias[col0 + j * 16 + lr];
      long obase = ((long)(bb * NH_ + head) * S_ + sr) * HD_;
      if (do_rope) {
#pragma unroll
        for (int j = 0; j < 8; ++j) {
          int d = j * 16 + lr;
          float rot = (j < 4) ? -vals[j + 4] : vals[j - 4];
          out[obase + d] = f2b(vals[j] * cs[sr * HD_ + d] + rot * sn[sr * HD_ + d]);
        }
      } else {
#pragma unroll
        for (int j = 0; j < 8; ++j) out[obase + j * 16 + lr] = f2b(vals[j]);
      }
    }
  }
}

// ---------------- General GEMM (LDS dbuf staged) ----------------
__global__ __launch_bounds__(256) void k_gemm(
    const short* __restrict__ A, const short* __restrict__ W,
    const float* __restrict__ bias,
    const short* __restrict__ T2, const short* __restrict__ Bm2,
    const float* __restrict__ resid, const short* gatebf, int do_silu,
    float* __restrict__ outf, short* outb,
    int N, int K) {
  __shared__ short As[2][128 * 32];
  __shared__ short Bs[2][128 * 32];
  int t = threadIdx.x;
  int lane = t & 63, wave = t >> 6;
  int wm = wave >> 1, wn = wave & 1;
  int row0 = blockIdx.y * 128;
  int col0 = blockIdx.x * 128;
  int lr = lane & 15, lk = (lane >> 4) << 3;
  int srow = t >> 2, skc = t & 3;
  const short* Ag0 = A + (long)(row0 + srow) * K + skc * 8;
  const short* Ag1 = A + (long)(row0 + 64 + srow) * K + skc * 8;
  const short* Wg0 = W + (long)(col0 + srow) * K + skc * 8;
  const short* Wg1 = W + (long)(col0 + 64 + srow) * K + skc * 8;
  auto stage = [&](int buf, int k0) {
    gl2lds16(Ag0 + k0, &As[buf][wave * 512]);
    gl2lds16(Ag1 + k0, &As[buf][2048 + wave * 512]);
    gl2lds16(Wg0 + k0, &Bs[buf][wave * 512]);
    gl2lds16(Wg1 + k0, &Bs[buf][2048 + wave * 512]);
  };
  f32x4 acc[4][4] = {};
  stage(0, 0);
  int cur = 0;
  for (int k0 = 0; k0 < K; k0 += 32) {
    asm volatile("s_waitcnt vmcnt(0) lgkmcnt(0)" ::: "memory");
    __syncthreads();                     // buf[cur] staged; prev-iter reads done
    if (k0 + 32 < K) stage(cur ^ 1, k0 + 32);
    bf16x8 a[4], b[4];
#pragma unroll
    for (int i = 0; i < 4; ++i) a[i] = *(const bf16x8*)(&As[cur][(wm * 64 + i * 16 + lr) * 32 + lk]);
#pragma unroll
    for (int j = 0; j < 4; ++j) b[j] = *(const bf16x8*)(&Bs[cur][(wn * 64 + j * 16 + lr) * 32 + lk]);
#pragma unroll
    for (int i = 0; i < 4; ++i)
#pragma unroll
      for (int j = 0; j < 4; ++j)
        acc[i][j] = __builtin_amdgcn_mfma_f32_16x16x32_bf16(a[i], b[j], acc[i][j], 0, 0, 0);
    cur ^= 1;
  }
  { // LoRA K-extension
    bf16x8 a[4], b[4];
#pragma unroll
    for (int i = 0; i < 4; ++i) a[i] = *(const bf16x8*)(T2 + (long)(row0 + wm * 64 + i * 16 + lr) * 32 + lk);
#pragma unroll
    for (int j = 0; j < 4; ++j) b[j] = *(const bf16x8*)(Bm2 + (long)(col0 + wn * 64 + j * 16 + lr) * 32 + lk);
#pragma unroll
    for (int i = 0; i < 4; ++i)
#pragma unroll
      for (int j = 0; j < 4; ++j)
        acc[i][j] = __builtin_amdgcn_mfma_f32_16x16x32_bf16(a[i], b[j], acc[i][j], 0, 0, 0);
  }
  int rquad = (lane >> 4) * 4;
#pragma unroll
  for (int i = 0; i < 4; ++i) {
#pragma unroll
    for (int j = 0; j < 4; ++j) {
      int col = col0 + wn * 64 + j * 16 + lr;
      float bc = bias[col];
#pragma unroll
      for (int tt = 0; tt < 4; ++tt) {
        int row = row0 + wm * 64 + i * 16 + rquad + tt;
        long idx = (long)row * N + col;
        float v2 = acc[i][j][tt] + bc;
        if (do_silu) v2 = v2 / (1.f + __expf(-v2));
        if (gatebf) v2 *= b2f((unsigned short)gatebf[idx]);
        if (resid) v2 += resid[idx];
        if (outf) outf[idx] = v2;
        else outb[idx] = f2b(v2);
      }
    }
  }
}

// ---------------- V transpose: [bh][s][d] -> [bh][d][s] (bf16) ----------------
__global__ __launch_bounds__(256) void k_vtrans(const short* __restrict__ in,
                                                short* __restrict__ out) {
  __shared__ short tb[64][72];
  int t = threadIdx.x;
  int s0 = blockIdx.x * 64, d0 = blockIdx.y * 64, bh = blockIdx.z;
  long ibase = (long)bh * S_ * HD_;
  long obase = (long)bh * HD_ * S_;
  int r = t >> 2, c = t & 3;
#pragma unroll
  for (int cc = 0; cc < 2; ++cc) {
    int ch = c + cc * 4;
    *(uint4*)&tb[r][ch * 8] = *(const uint4*)(in + ibase + (long)(s0 + r) * HD_ + d0 + ch * 8);
  }
  __syncthreads();
  int d = t >> 2;
#pragma unroll
  for (int cc = 0; cc < 2; ++cc) {
    int ch = c + cc * 4;
    short v[8];
#pragma unroll
    for (int ii = 0; ii < 8; ++ii) v[ii] = tb[ch * 8 + ii][d];
    *(uint4*)(out + obase + (long)(d0 + d) * S_ + s0 + ch * 8) = *(uint4*)v;
  }
}

// ---------------- MFMA flash attention (causal) + K/V double-buffer --------
__global__ __launch_bounds__(256) void k_attn(const short* __restrict__ Q,
                                              const short* __restrict__ Kg,
                                              const short* __restrict__ Vt,
                                              short* __restrict__ att) {
  __shared__ __align__(16) short Kls[2][4][64 * 32];   // [buf][ks][key*32]
  __shared__ __align__(16) short Vls[2][2][128 * 32];  // [buf][kv][d*32]
  __shared__ __align__(16) short Pl[4][32 * 72];       // per-wave [q][72]
  __shared__ float al[4][32];
  __shared__ float ll[4][32];
  int t = threadIdx.x, lane = t & 63, wave = t >> 6;
  int lr = lane & 15, quad = lane >> 4;
  int bh = blockIdx.x & 31;
  int qb = 15 - (blockIdx.x >> 5);     // heavy tiles dispatched first
  int q0 = qb * 128;
  int qlo = q0 + wave * 32;
  long base = (long)bh * S_ * HD_;
  long vbase = (long)bh * HD_ * S_;
  const float c1 = 0.08838834764831845f * 1.44269504089f;  // scale*log2e
  // Q fragments (registers, once per block)
  bf16x8 qf[2][4];
#pragma unroll
  for (int i = 0; i < 2; ++i)
#pragma unroll
    for (int ks = 0; ks < 4; ++ks)
      qf[i][ks] = *(const bf16x8*)(Q + base + (long)(qlo + i * 16 + lr) * HD_ + ks * 32 + quad * 8);
  f32x4 oacc[8][2] = {};
  float m_i[2][4], l_i[2][4];
#pragma unroll
  for (int i = 0; i < 2; ++i)
#pragma unroll
    for (int tt = 0; tt < 4; ++tt) { m_i[i][tt] = -3.0e38f; l_i[i][tt] = 0.f; }
  int sk_row = lane >> 2, sk_c = lane & 3;
  auto stage = [&](int buf, int kb) {
    int kk0 = kb << 6;
#pragma unroll
    for (int i = 0; i < 4; ++i)
      gl2lds16(Kg + base + (long)(kk0 + i * 16 + sk_row) * HD_ + wave * 32 + sk_c * 8,
               &Kls[buf][wave][i * 512]);
#pragma unroll
    for (int kv = 0; kv < 2; ++kv)
#pragma unroll
      for (int db = 0; db < 2; ++db)
        gl2lds16(Vt + vbase + (long)(wave * 32 + db * 16 + sk_row) * S_ + kk0 + kv * 32 + sk_c * 8,
                 &Vls[buf][kv][(wave * 32 + db * 16) * 32]);
  };
  int kbmax = (q0 + 127) >> 6;
  stage(0, 0);
  int cur = 0;
  for (int kb = 0; kb <= kbmax; ++kb) {
    int kk0 = kb << 6;
    asm volatile("s_waitcnt vmcnt(0) lgkmcnt(0)" ::: "memory");
    __syncthreads();                       // buf[cur] staged; prev-iter reads done
    if (kb < kbmax) stage(cur ^ 1, kb + 1);
    if (kk0 <= qlo + 31) {
      // S = Q K^T
      f32x4 s[2][4] = {};
#pragma unroll
      for (int ks = 0; ks < 4; ++ks) {
        bf16x8 kf[4];
#pragma unroll
        for (int j = 0; j < 4; ++j) kf[j] = *(const bf16x8*)&Kls[cur][ks][(j * 16 + lr) * 32 + quad * 8];
#pragma unroll
        for (int i = 0; i < 2; ++i)
#pragma unroll
          for (int j = 0; j < 4; ++j)
            s[i][j] = __builtin_amdgcn_mfma_f32_16x16x32_bf16(qf[i][ks], kf[j], s[i][j], 0, 0, 0);
      }
      // causal mask (only diagonal-region tiles)
      if (kk0 + 63 > qlo) {
#pragma unroll
        for (int i = 0; i < 2; ++i)
#pragma unroll
          for (int j = 0; j < 4; ++j) {
            int key = kk0 + j * 16 + lr;
#pragma unroll
            for (int tt = 0; tt < 4; ++tt) {
              int qrow = qlo + i * 16 + quad * 4 + tt;
              if (key > qrow) s[i][j][tt] = -1.0e30f;
            }
          }
      }
      // online softmax per row (raw domain, scale in exp2 args)
#pragma unroll
      for (int i = 0; i < 2; ++i) {
#pragma unroll
        for (int tt = 0; tt < 4; ++tt) {
          float mx = fmaxf(fmaxf(s[i][0][tt], s[i][1][tt]), fmaxf(s[i][2][tt], s[i][3][tt]));
#pragma unroll
          for (int o = 1; o < 16; o <<= 1) mx = fmaxf(mx, __shfl_xor(mx, o));
          float mold = m_i[i][tt];
          float mnew = fmaxf(mold, mx);
          float alpha = exp2f((mold - mnew) * c1);
          float mc = mnew * c1;
          float rs = 0.f;
#pragma unroll
          for (int j = 0; j < 4; ++j) {
            float p = exp2f(s[i][j][tt] * c1 - mc);
            s[i][j][tt] = p;
            rs += p;
          }
#pragma unroll
          for (int o = 1; o < 16; o <<= 1) rs += __shfl_xor(rs, o);
          l_i[i][tt] = l_i[i][tt] * alpha + rs;
          m_i[i][tt] = mnew;
          if (lr == 0) al[wave][i * 16 + quad * 4 + tt] = alpha;
        }
      }
      // P -> LDS (bf16, padded rows)
#pragma unroll
      for (int i = 0; i < 2; ++i)
#pragma unroll
        for (int j = 0; j < 4; ++j)
#pragma unroll
          for (int tt = 0; tt < 4; ++tt)
            Pl[wave][(i * 16 + quad * 4 + tt) * 72 + j * 16 + lr] = f2b(s[i][j][tt]);
      // rescale O accumulator by alpha[q]
#pragma unroll
      for (int i2 = 0; i2 < 2; ++i2) {
        float aq = al[wave][i2 * 16 + lr];
#pragma unroll
        for (int mi = 0; mi < 8; ++mi) {
          oacc[mi][i2][0] *= aq; oacc[mi][i2][1] *= aq;
          oacc[mi][i2][2] *= aq; oacc[mi][i2][3] *= aq;
        }
      }
      // O^T += V^T * P   (A = V^T tile, B = P)
#pragma unroll
      for (int kv = 0; kv < 2; ++kv) {
        bf16x8 pf[2];
#pragma unroll
        for (int i2 = 0; i2 < 2; ++i2)
          pf[i2] = *(const bf16x8*)&Pl[wave][(i2 * 16 + lr) * 72 + kv * 32 + quad * 8];
#pragma unroll
        for (int mi = 0; mi < 8; ++mi) {
          bf16x8 vfr = *(const bf16x8*)&Vls[cur][kv][(mi * 16 + lr) * 32 + quad * 8];
#pragma unroll
          for (int i2 = 0; i2 < 2; ++i2)
            oacc[mi][i2] = __builtin_amdgcn_mfma_f32_16x16x32_bf16(vfr, pf[i2], oacc[mi][i2], 0, 0, 0);
        }
      }
    }
    cur ^= 1;
  }
  // epilogue: divide by l, store O[q][d] as short4 along d
#pragma unroll
  for (int i = 0; i < 2; ++i)
#pragma unroll
    for (int tt = 0; tt < 4; ++tt)
      if (lr == 0) ll[wave][i * 16 + quad * 4 + tt] = l_i[i][tt];
  int b = bh >> 4, h = bh & (NH_ - 1);
#pragma unroll
  for (int i2 = 0; i2 < 2; ++i2) {
    float inv = 1.f / ll[wave][i2 * 16 + lr];
    int q_abs = qlo + i2 * 16 + lr;
    long ob = ((long)(b * S_ + q_abs)) * H_ + h * HD_;
#pragma unroll
    for (int mi = 0; mi < 8; ++mi) {
      short4 o4;
      o4.x = f2b(oacc[mi][i2][0] * inv);
      o4.y = f2b(oacc[mi][i2][1] * inv);
      o4.z = f2b(oacc[mi][i2][2] * inv);
      o4.w = f2b(oacc[mi][i2][3] * inv);
      *(short4*)(att + ob + mi * 16 + quad * 4) = o4;
    }
  }
}

// ---------------- host ----------------
extern "C" void kernel_launch(void* const* d_in, const int* in_sizes, int n_in,
                              void* d_out, int out_size, void* d_ws, size_t ws_size,
                              hipStream_t stream) {
  const float* x    = (const float*)d_in[0];
  const float* nw1  = (const float*)d_in[1];
  const float* nw2  = (const float*)d_in[2];
  const float* cosb = (const float*)d_in[3];
  const float* sinb = (const float*)d_in[4];
  const float *W[7], *Bias[7], *La[7], *Lb[7];
  for (int p = 0; p < 7; ++p) {
    W[p]    = (const float*)d_in[5 + p * 4];
    Bias[p] = (const float*)d_in[6 + p * 4];
    La[p]   = (const float*)d_in[7 + p * 4];
    Lb[p]   = (const float*)d_in[8 + p * 4];
  }
  const int wsz[7] = {H_*H_, H_*H_, H_*H_, H_*H_, INTER_*H_, INTER_*H_, INTER_*H_};

  char* ws = (char*)d_ws;
  size_t off = 0;
  short* wbuf = (short*)(ws + off); off += (size_t)INTER_ * H_ * 2;
  short* T2   = (short*)(ws + off); off += (size_t)M_ * 32 * 2;
  short* Bm2  = (short*)(ws + off); off += (size_t)INTER_ * 32 * 2;
  short* xn   = (short*)(ws + off); off += (size_t)M_ * H_ * 2;
  char*  regC = ws + off;           off += (size_t)M_ * H_ * 2 * 3;
  short* gact = (short*)(ws + off); off += (size_t)M_ * INTER_ * 2;
  short* qr = (short*)regC;
  short* kr = (short*)(regC + (size_t)M_ * H_ * 2);
  short* vr = (short*)(regC + (size_t)M_ * H_ * 2 * 2);
  float* xmed = (float*)regC;
  short* vt   = gact;               // vt lifetime ends before gact starts
  short* attb = xn;
  float* outp = (float*)d_out;

  auto conv = [&](int p) {
    k_f2b<<<dim3((wsz[p] / 4 + 255) / 256), dim3(256), 0, stream>>>(W[p], wbuf, wsz[p]);
  };
  auto lora = [&](int p, const short* Ain, int K, int N) {
    k_lora_t<<<dim3(M_), dim3(256), 0, stream>>>(Ain, La[p], T2, K);
    k_prep_bm2<<<dim3((N * 32 + 255) / 256), dim3(256), 0, stream>>>(Lb[p], Bm2, N);
  };

  // 1. RMSNorm 1
  k_rmsnorm<<<dim3(M_), dim3(256), 0, stream>>>(x, nw1, xn);
  // 2. Q,K,V projections fused with RoPE + transpose -> [B,NH,S,HD]
  conv(0); lora(0, xn, H_, H_);
  k_gemm_qkv<<<dim3(NH_, M_ / 128), dim3(256), 0, stream>>>(xn, wbuf, Bias[0], T2, Bm2, cosb, sinb, qr, 1);
  conv(1); lora(1, xn, H_, H_);
  k_gemm_qkv<<<dim3(NH_, M_ / 128), dim3(256), 0, stream>>>(xn, wbuf, Bias[1], T2, Bm2, cosb, sinb, kr, 1);
  conv(2); lora(2, xn, H_, H_);
  k_gemm_qkv<<<dim3(NH_, M_ / 128), dim3(256), 0, stream>>>(xn, wbuf, Bias[2], T2, Bm2, cosb, sinb, vr, 0);
  // 3. V transpose -> vt [bh][d][s]
  k_vtrans<<<dim3(S_ / 64, HD_ / 64, B_ * NH_), dim3(256), 0, stream>>>(vr, vt);
  // 4. MFMA flash attention (K/V dbuf, heavy-first order) -> attb [B,S,H] bf16
  k_attn<<<dim3(B_ * NH_ * (S_ / 128)), dim3(256), 0, stream>>>(qr, kr, vt, attb);
  // 5. O projection + residual(x) -> xmed fp32
  conv(3); lora(3, attb, H_, H_);
  k_gemm<<<dim3(H_ / 128, M_ / 128), dim3(256), 0, stream>>>(
      attb, wbuf, Bias[3], T2, Bm2, x, nullptr, 0, xmed, nullptr, H_, H_);
  // 6. RMSNorm 2 -> xn
  k_rmsnorm<<<dim3(M_), dim3(256), 0, stream>>>(xmed, nw2, xn);
  // 7. gate -> silu(gate) bf16
  conv(4); lora(4, xn, H_, INTER_);
  k_gemm<<<dim3(INTER_ / 128, M_ / 128), dim3(256), 0, stream>>>(
      xn, wbuf, Bias[4], T2, Bm2, nullptr, nullptr, 1, nullptr, gact, INTER_, H_);
  // 8. up * silu(gate) -> gact in place
  conv(5); lora(5, xn, H_, INTER_);
  k_gemm<<<dim3(INTER_ / 128, M_ / 128), dim3(256), 0, stream>>>(
      xn, wbuf, Bias[5], T2, Bm2, nullptr, gact, 0, nullptr, gact, INTER_, H_);
  // 9. down + residual(xmed) -> d_out fp32
  conv(6); lora(6, gact, INTER_, H_);
  k_gemm<<<dim3(H_ / 128, M_ / 128), dim3(256), 0, stream>>>(
      gact, wbuf, Bias[6], T2, Bm2, xmed, nullptr, 0, outp, nullptr, H_, INTER_);
}